// Round 1
// baseline (1578.811 us; speedup 1.0000x reference)
//
#include <hip/hip_runtime.h>
#include <hip/hip_bf16.h>

#define S_DIM 2048
#define D_DIM 128
#define QBLK 64   // 4 waves x 16 rows
#define NW 4

typedef __attribute__((ext_vector_type(8))) __bf16 bf16x8;
typedef __attribute__((ext_vector_type(4))) float f32x4;

__device__ __forceinline__ bf16x8 load_cvt8(const float* __restrict__ p) {
    float4 a = *reinterpret_cast<const float4*>(p);
    float4 b = *reinterpret_cast<const float4*>(p + 4);
    bf16x8 r;
    r[0] = (__bf16)a.x; r[1] = (__bf16)a.y; r[2] = (__bf16)a.z; r[3] = (__bf16)a.w;
    r[4] = (__bf16)b.x; r[5] = (__bf16)b.y; r[6] = (__bf16)b.z; r[7] = (__bf16)b.w;
    return r;
}

__device__ __forceinline__ bf16x8 load_cvt8_scaled(const float* __restrict__ p, float s) {
    float4 a = *reinterpret_cast<const float4*>(p);
    float4 b = *reinterpret_cast<const float4*>(p + 4);
    bf16x8 r;
    r[0] = (__bf16)(a.x * s); r[1] = (__bf16)(a.y * s);
    r[2] = (__bf16)(a.z * s); r[3] = (__bf16)(a.w * s);
    r[4] = (__bf16)(b.x * s); r[5] = (__bf16)(b.y * s);
    r[6] = (__bf16)(b.z * s); r[7] = (__bf16)(b.w * s);
    return r;
}

__global__ __launch_bounds__(256)
void attn_fwd(const float* __restrict__ Q, const float* __restrict__ K,
              const float* __restrict__ V, float* __restrict__ O) {
    __shared__ __bf16 p_lds[NW][16][40];   // stride 40 -> 2-way bank alias only

    const int tid  = threadIdx.x;
    const int lane = tid & 63;
    const int wv   = tid >> 6;
    const int g    = lane >> 4;   // 0..3
    const int c    = lane & 15;   // 0..15
    const int bh   = blockIdx.y;
    const int q0   = blockIdx.x * QBLK + wv * 16;

    const size_t base = (size_t)bh * S_DIM * D_DIM;
    const float* Qb = Q + base;
    const float* Kb = K + base;
    const float* Vb = V + base;

    // Q A-fragments: lane holds Q[q0 + c][ch*32 + g*8 + j], scaled by 1/sqrt(D)
    const float qs = 0.08838834764831845f;
    bf16x8 aq[4];
    #pragma unroll
    for (int ch = 0; ch < 4; ++ch)
        aq[ch] = load_cvt8_scaled(Qb + (size_t)(q0 + c) * D_DIM + ch * 32 + g * 8, qs);

    f32x4 o_acc[8];
    #pragma unroll
    for (int i = 0; i < 8; ++i) o_acc[i] = f32x4{0.f, 0.f, 0.f, 0.f};
    float m_run[4], l_run[4];
    #pragma unroll
    for (int r = 0; r < 4; ++r) { m_run[r] = -3.0e38f; l_run[r] = 0.f; }

    const int ntiles = (q0 + 15) / 32 + 1;  // kv32 tiles up to the diagonal

    for (int t = 0; t < ntiles; ++t) {
        const int kvb = t * 32;

        // ---- scores S = (Q/sqrt(d)) K^T : two 16x16 fragments ----
        f32x4 s[2];
        #pragma unroll
        for (int n = 0; n < 2; ++n) {
            f32x4 acc = f32x4{0.f, 0.f, 0.f, 0.f};
            const float* kp = Kb + (size_t)(kvb + n * 16 + c) * D_DIM + g * 8;
            #pragma unroll
            for (int ch = 0; ch < 4; ++ch) {
                bf16x8 bk = load_cvt8(kp + ch * 32);
                acc = __builtin_amdgcn_mfma_f32_16x16x32_bf16(aq[ch], bk, acc, 0, 0, 0);
            }
            s[n] = acc;
        }

        // ---- causal mask on diagonal-crossing tiles ----
        if (kvb + 31 > q0) {
            #pragma unroll
            for (int n = 0; n < 2; ++n) {
                const int kvc = kvb + n * 16 + c;
                #pragma unroll
                for (int r = 0; r < 4; ++r) {
                    const int qr = q0 + g * 4 + r;
                    if (kvc > qr) s[n][r] = -1.0e30f;
                }
            }
        }

        // ---- online softmax (row = g*4+r, spread across 16 lanes) ----
        float sf[4];
        #pragma unroll
        for (int r = 0; r < 4; ++r) {
            float tm = fmaxf(s[0][r], s[1][r]);
            tm = fmaxf(tm, __shfl_xor(tm, 1));
            tm = fmaxf(tm, __shfl_xor(tm, 2));
            tm = fmaxf(tm, __shfl_xor(tm, 4));
            tm = fmaxf(tm, __shfl_xor(tm, 8));
            const float mn = fmaxf(m_run[r], tm);
            sf[r] = __expf(m_run[r] - mn);
            m_run[r] = mn;
            const float p0 = __expf(s[0][r] - mn);
            const float p1 = __expf(s[1][r] - mn);
            s[0][r] = p0; s[1][r] = p1;
            float rs = p0 + p1;
            rs += __shfl_xor(rs, 1);
            rs += __shfl_xor(rs, 2);
            rs += __shfl_xor(rs, 4);
            rs += __shfl_xor(rs, 8);
            l_run[r] = l_run[r] * sf[r] + rs;
        }
        #pragma unroll
        for (int d0 = 0; d0 < 8; ++d0)
            #pragma unroll
            for (int r = 0; r < 4; ++r) o_acc[d0][r] *= sf[r];

        // ---- P (D-layout) -> LDS -> A-fragment layout ----
        #pragma unroll
        for (int n = 0; n < 2; ++n)
            #pragma unroll
            for (int r = 0; r < 4; ++r)
                p_lds[wv][g * 4 + r][n * 16 + c] = (__bf16)s[n][r];

        const bf16x8 pa = *reinterpret_cast<const bf16x8*>(&p_lds[wv][c][g * 8]);

        // ---- O += P V ----
        #pragma unroll
        for (int d0 = 0; d0 < 8; ++d0) {
            const float* vp = Vb + (size_t)(kvb + g * 8) * D_DIM + d0 * 16 + c;
            bf16x8 bv;
            #pragma unroll
            for (int j = 0; j < 8; ++j) bv[j] = (__bf16)vp[(size_t)j * D_DIM];
            o_acc[d0] = __builtin_amdgcn_mfma_f32_16x16x32_bf16(pa, bv, o_acc[d0], 0, 0, 0);
        }
    }

    // ---- epilogue: O / l ----
    #pragma unroll
    for (int r = 0; r < 4; ++r) {
        const float inv = 1.0f / l_run[r];
        float* op = O + base + (size_t)(q0 + g * 4 + r) * D_DIM + c;
        #pragma unroll
        for (int d0 = 0; d0 < 8; ++d0) op[d0 * 16] = o_acc[d0][r] * inv;
    }
}

extern "C" void kernel_launch(void* const* d_in, const int* in_sizes, int n_in,
                              void* d_out, int out_size, void* d_ws, size_t ws_size,
                              hipStream_t stream) {
    const float* Q = (const float*)d_in[0];
    const float* K = (const float*)d_in[1];
    const float* V = (const float*)d_in[2];
    float* O = (float*)d_out;
    const int bh = in_sizes[0] / (S_DIM * D_DIM);   // B*H = 64
    dim3 grid(S_DIM / QBLK, bh);
    attn_fwd<<<grid, 256, 0, stream>>>(Q, K, V, O);
}

// Round 3
// 558.112 us; speedup vs baseline: 2.8288x; 2.8288x over previous
//
#include <hip/hip_runtime.h>
#include <hip/hip_bf16.h>
#include <stdint.h>

#define S_DIM 2048
#define D_DIM 128
#define QBLK 128
#define KVBLK 32
#define NW 8
#define NXQ (S_DIM / QBLK)

typedef __attribute__((ext_vector_type(8))) __bf16 bf16x8;
typedef __attribute__((ext_vector_type(4))) float f32x4;
typedef __attribute__((ext_vector_type(2))) unsigned int u32x2;
typedef __attribute__((ext_vector_type(4))) unsigned int u32x4;

__device__ __forceinline__ uint32_t lds_off(const void* p) {
    return (uint32_t)(uintptr_t)p;   // low 32 bits of LDS flat addr = byte offset
}

__device__ __forceinline__ bf16x8 load_cvt8_scaled(const float* __restrict__ p, float s) {
    float4 a = *reinterpret_cast<const float4*>(p);
    float4 b = *reinterpret_cast<const float4*>(p + 4);
    bf16x8 r;
    r[0] = (__bf16)(a.x * s); r[1] = (__bf16)(a.y * s);
    r[2] = (__bf16)(a.z * s); r[3] = (__bf16)(a.w * s);
    r[4] = (__bf16)(b.x * s); r[5] = (__bf16)(b.y * s);
    r[6] = (__bf16)(b.z * s); r[7] = (__bf16)(b.w * s);
    return r;
}

__global__ __launch_bounds__(512, 2)
void attn_fwd(const float* __restrict__ Q, const float* __restrict__ K,
              const float* __restrict__ V, float* __restrict__ O) {
    // K tile: row-major [KVBLK][128] bf16, byte ^= ((row&7)<<4) swizzle
    // V tile: tr_b16 layout L(kv,d) = 512*(d>>4) + 256*((kv>>2)&1) + 64*(kv>>3) + 16*(kv&3) + (d&15)
    __shared__ __bf16 k_lds[2][KVBLK * D_DIM];
    __shared__ __bf16 v_lds[2][KVBLK * D_DIM];
    __shared__ __bf16 p_lds[NW][16][40];

    const int tid  = threadIdx.x;
    const int lane = tid & 63;
    const int wv   = tid >> 6;
    const int g    = lane >> 4;   // 0..3
    const int c    = lane & 15;   // 0..15
    const int bh   = blockIdx.y;
    const int q0b  = (NXQ - 1 - (int)blockIdx.x) * QBLK;  // big blocks first
    const int q0w  = q0b + wv * 16;

    const size_t base = (size_t)bh * S_DIM * D_DIM;
    const float* Qb = Q + base;
    const float* Kb = K + base;
    const float* Vb = V + base;

    // ---- staging assignment: thread -> (row skv, 8-float chunk sd8) ----
    const int skv = tid >> 4;   // 0..31
    const int sd8 = tid & 15;   // 0..15
    const float* kgp = Kb + (size_t)skv * D_DIM + sd8 * 8;
    const float* vgp = Vb + (size_t)skv * D_DIM + sd8 * 8;
    const uint32_t koff = (uint32_t)((skv * 256 + sd8 * 16) ^ ((skv & 7) << 4));
    const uint32_t voff = (uint32_t)((((sd8 >> 1) * 2 + ((skv >> 2) & 1)) * 256
                            + (sd8 & 1) * 8 + (skv & 3) * 16 + (skv >> 3) * 64) * 2);

    float4 kf0, kf1, vf0, vf1;
    auto stage_load = [&](int t) {
        const size_t off = (size_t)t * KVBLK * D_DIM;
        kf0 = *reinterpret_cast<const float4*>(kgp + off);
        kf1 = *reinterpret_cast<const float4*>(kgp + off + 4);
        vf0 = *reinterpret_cast<const float4*>(vgp + off);
        vf1 = *reinterpret_cast<const float4*>(vgp + off + 4);
    };
    auto stage_write = [&](int buf) {
        bf16x8 kb, vb8;
        kb[0] = (__bf16)kf0.x; kb[1] = (__bf16)kf0.y; kb[2] = (__bf16)kf0.z; kb[3] = (__bf16)kf0.w;
        kb[4] = (__bf16)kf1.x; kb[5] = (__bf16)kf1.y; kb[6] = (__bf16)kf1.z; kb[7] = (__bf16)kf1.w;
        vb8[0] = (__bf16)vf0.x; vb8[1] = (__bf16)vf0.y; vb8[2] = (__bf16)vf0.z; vb8[3] = (__bf16)vf0.w;
        vb8[4] = (__bf16)vf1.x; vb8[5] = (__bf16)vf1.y; vb8[6] = (__bf16)vf1.z; vb8[7] = (__bf16)vf1.w;
        *reinterpret_cast<bf16x8*>((char*)&k_lds[buf][0] + koff) = kb;
        *reinterpret_cast<bf16x8*>((char*)&v_lds[buf][0] + voff) = vb8;
    };

    // ---- Q fragments (scale folded) ----
    const float qs = 0.08838834764831845f;
    bf16x8 aq[4];
    #pragma unroll
    for (int ch = 0; ch < 4; ++ch)
        aq[ch] = load_cvt8_scaled(Qb + (size_t)(q0w + c) * D_DIM + ch * 32 + g * 8, qs);

    f32x4 o_acc[8];
    #pragma unroll
    for (int i = 0; i < 8; ++i) o_acc[i] = f32x4{0.f, 0.f, 0.f, 0.f};
    float m_run[4], l_run[4];
    #pragma unroll
    for (int r = 0; r < 4; ++r) { m_run[r] = -3.0e38f; l_run[r] = 0.f; }

    const int nt = q0b / KVBLK + QBLK / KVBLK;   // tiles to cover block's diagonal

    // prologue: stage tile 0 into buf 0
    stage_load(0);
    stage_write(0);

    int cur = 0;
    for (int t = 0; t < nt; ++t) {
        const int kvb = t * KVBLK;
        const bool have_next = (t + 1 < nt);
        if (have_next) stage_load(t + 1);   // loads in flight across compute (T14)

        __syncthreads();                    // tile t's LDS writes visible

        // ---- QK^T from LDS (swizzled b128 reads) ----
        const char* kbp = (const char*)&k_lds[cur][0];
        f32x4 s[2];
        #pragma unroll
        for (int n = 0; n < 2; ++n) {
            f32x4 acc = f32x4{0.f, 0.f, 0.f, 0.f};
            #pragma unroll
            for (int ch = 0; ch < 4; ++ch) {
                const uint32_t off = (uint32_t)(((n * 16 + c) * 256 + ch * 64 + g * 16) ^ ((c & 7) << 4));
                bf16x8 bk = *reinterpret_cast<const bf16x8*>(kbp + off);
                acc = __builtin_amdgcn_mfma_f32_16x16x32_bf16(aq[ch], bk, acc, 0, 0, 0);
            }
            s[n] = acc;
        }

        // ---- causal mask ----
        if (kvb + KVBLK - 1 > q0w) {
            #pragma unroll
            for (int n = 0; n < 2; ++n) {
                const int kvc = kvb + n * 16 + c;
                #pragma unroll
                for (int r = 0; r < 4; ++r) {
                    if (kvc > q0w + g * 4 + r) s[n][r] = -1.0e30f;
                }
            }
        }

        // ---- online softmax ----
        float sf[4];
        #pragma unroll
        for (int r = 0; r < 4; ++r) {
            float tm = fmaxf(s[0][r], s[1][r]);
            tm = fmaxf(tm, __shfl_xor(tm, 1));
            tm = fmaxf(tm, __shfl_xor(tm, 2));
            tm = fmaxf(tm, __shfl_xor(tm, 4));
            tm = fmaxf(tm, __shfl_xor(tm, 8));
            const float mn = fmaxf(m_run[r], tm);
            sf[r] = __expf(m_run[r] - mn);
            m_run[r] = mn;
            const float p0 = __expf(s[0][r] - mn);
            const float p1 = __expf(s[1][r] - mn);
            s[0][r] = p0; s[1][r] = p1;
            float rs = p0 + p1;
            rs += __shfl_xor(rs, 1);
            rs += __shfl_xor(rs, 2);
            rs += __shfl_xor(rs, 4);
            rs += __shfl_xor(rs, 8);
            l_run[r] = l_run[r] * sf[r] + rs;
        }
        #pragma unroll
        for (int d0 = 0; d0 < 8; ++d0)
            #pragma unroll
            for (int r = 0; r < 4; ++r) o_acc[d0][r] *= sf[r];

        // ---- P -> LDS (D-layout) -> A-fragment ----
        #pragma unroll
        for (int n = 0; n < 2; ++n)
            #pragma unroll
            for (int r = 0; r < 4; ++r)
                p_lds[wv][g * 4 + r][n * 16 + c] = (__bf16)s[n][r];
        const bf16x8 pa = *reinterpret_cast<const bf16x8*>(&p_lds[wv][c][g * 8]);

        // ---- PV: V B-fragments via HW transpose reads (per-lane addr = base + lane*8B) ----
        const uint32_t vbase = lds_off(&v_lds[cur][0]) + (uint32_t)lane * 8u;
        u32x2 tr[16];
        #pragma unroll
        for (int d0 = 0; d0 < 8; ++d0) {
            const uint32_t a0 = vbase + d0 * 1024;
            asm volatile("ds_read_b64_tr_b16 %0, %1" : "=v"(tr[2 * d0]) : "v"(a0));
            asm volatile("ds_read_b64_tr_b16 %0, %1 offset:512" : "=v"(tr[2 * d0 + 1]) : "v"(a0));
        }
        asm volatile("s_waitcnt lgkmcnt(0)");
        __builtin_amdgcn_sched_barrier(0);
        #pragma unroll
        for (int d0 = 0; d0 < 8; ++d0) {
            u32x4 bu;
            bu[0] = tr[2 * d0][0]; bu[1] = tr[2 * d0][1];
            bu[2] = tr[2 * d0 + 1][0]; bu[3] = tr[2 * d0 + 1][1];
            bf16x8 bv = __builtin_bit_cast(bf16x8, bu);
            o_acc[d0] = __builtin_amdgcn_mfma_f32_16x16x32_bf16(pa, bv, o_acc[d0], 0, 0, 0);
        }

        // ---- write next tile into the other buffer (vmcnt waits inserted here) ----
        if (have_next) stage_write(cur ^ 1);
        cur ^= 1;
    }

    // ---- epilogue ----
    #pragma unroll
    for (int r = 0; r < 4; ++r) {
        const float inv = 1.0f / l_run[r];
        float* op = O + base + (size_t)(q0w + g * 4 + r) * D_DIM + c;
        #pragma unroll
        for (int d0 = 0; d0 < 8; ++d0) op[d0 * 16] = o_acc[d0][r] * inv;
    }
}

extern "C" void kernel_launch(void* const* d_in, const int* in_sizes, int n_in,
                              void* d_out, int out_size, void* d_ws, size_t ws_size,
                              hipStream_t stream) {
    const float* Q = (const float*)d_in[0];
    const float* K = (const float*)d_in[1];
    const float* V = (const float*)d_in[2];
    float* O = (float*)d_out;
    const int bh = in_sizes[0] / (S_DIM * D_DIM);   // B*H = 64
    dim3 grid(NXQ, bh);
    attn_fwd<<<grid, 512, 0, stream>>>(Q, K, V, O);
}